// Round 13
// baseline (181.834 us; speedup 1.0000x reference)
//
#include <hip/hip_runtime.h>
#include <cstdint>
#include <cstddef>

typedef __attribute__((ext_vector_type(8))) short short8;
typedef __attribute__((ext_vector_type(8))) unsigned short ushort8;
typedef __attribute__((ext_vector_type(4))) float f32x4;

#define EPSV 1e-5f
#define NB 1024
#define NEDGE 1048576
#define EPG 1024
#define CNTF 65536.0f
#define REP 32           // stats replica slots (contention spreading)

// ---------------------------------------------------------------------------
// R13: R12 champion (164.4us) with ONE change: k_mlp1 reads its B-operand
// (wbf1t weight fragments) DIRECTLY from global instead of staging
// Ws[128][72] (18.4KB) into LDS per ck-iteration.
//   - all 4 waves read identical Ws rows (broadcast); 16 bx-blocks share
//     each panel; wbf1t = 2MiB L2-resident -> same L2-hot-direct pattern
//     validated on k_convm in R12.
//   - LDS ~28KB -> ~9.7KB: occupancy 5 -> 8 blocks/CU (wave-cap)
//   - deletes 64 staged stores/thread/ck + their barrier dependency
// Arithmetic unchanged. All other kernels byte-identical to R12.
// ---------------------------------------------------------------------------

__device__ __forceinline__ ushort f2bf(float f) {
  uint u = __float_as_uint(f);
  return (ushort)((u + 0x7FFFu + ((u >> 16) & 1u)) >> 16);
}
__device__ __forceinline__ float bf2f(ushort u) {
  return __uint_as_float((uint)u << 16);
}

// ---------------------------------------------------------------------------
// k_prepw: all weight preprocessing + stats zeroing in ONE kernel.
//  blocks 0..255   : wm1 -> wbf1t bf16 chunk-major [kc][n][kk]
//  blocks 256..319 : wm2,wm3 -> wbf2t/wbf3t bf16 chunk-major [kc][n][kk].
//  block  320      : wp -> wpt bf16 [a][k].
//  blocks 321..416 : conv weights [o][c][kk] -> bf16 cwt [o][kk*64+c].
//  block  417      : zero stats (3*REP*128 floats).
// ---------------------------------------------------------------------------
__global__ __launch_bounds__(256) void k_prepw(
    const float* __restrict__ wm1, const float* __restrict__ wm2,
    const float* __restrict__ wm3, const float* __restrict__ wp,
    const float* __restrict__ c2w, const float* __restrict__ c3w,
    ushort* __restrict__ wbf1t, ushort* __restrict__ wbf2t,
    ushort* __restrict__ wbf3t, ushort* __restrict__ wptbf,
    ushort* __restrict__ cwt2, ushort* __restrict__ cwt3,
    float* __restrict__ stats)
{
  __shared__ ushort T[64][72];
  const int tid = threadIdx.x;
  const int bb = blockIdx.x;

  if (bb < 256) {
    const int kc = bb >> 2, n0 = (bb & 3) << 6;
    const int kk = tid >> 2, np = (tid & 3) << 4;
    const float* srow = wm1 + (((size_t)(kk << 6) + kc) << 8) + n0 + np;
#pragma unroll
    for (int i = 0; i < 4; ++i) {
      const float4 v = *(const float4*)(srow + (i << 2));
      const int n = np + (i << 2);
      T[n + 0][kk] = f2bf(v.x); T[n + 1][kk] = f2bf(v.y);
      T[n + 2][kk] = f2bf(v.z); T[n + 3][kk] = f2bf(v.w);
    }
    __syncthreads();
    ushort* dst = wbf1t + ((size_t)kc << 14) + (n0 << 6);
    const int nl = tid >> 2, qk = (tid & 3) << 4;
    *(ushort8*)(dst + (nl << 6) + qk) = *(ushort8*)&T[nl][qk];
    *(ushort8*)(dst + (nl << 6) + qk + 8) = *(ushort8*)&T[nl][qk + 8];
    return;
  }
  if (bb < 320) {
    const int base = (((bb - 256) << 8) + tid) << 3;
    const int m = base >> 16;
    const int rem = base & 65535;
    const int kc = rem >> 14, within = rem & 16383;
    const int n = within >> 6, kk0 = within & 63;
    const float* src = m ? wm3 : wm2;
    ushort* dst = m ? wbf3t : wbf2t;
    ushort tmp[8];
#pragma unroll
    for (int j = 0; j < 8; ++j)
      tmp[j] = f2bf(src[(((kc << 6) | (kk0 + j)) << 8) + n]);
    *(ushort8*)&dst[rem] = *(ushort8*)&tmp[0];
    return;
  }
  if (bb == 320) {
    const int a = tid & 15, k0 = (tid >> 4) << 4;
    ushort tmp[16];
#pragma unroll
    for (int j = 0; j < 16; ++j) tmp[j] = f2bf(wp[((k0 + j) << 4) + a]);
    *(ushort8*)&wptbf[(a << 8) + k0] = *(ushort8*)&tmp[0];
    *(ushort8*)&wptbf[(a << 8) + k0 + 8] = *(ushort8*)&tmp[8];
    return;
  }
  if (bb == 417) {
    float4 z4 = make_float4(0.f, 0.f, 0.f, 0.f);
#pragma unroll
    for (int i = 0; i < 12; ++i) ((float4*)stats)[(i << 8) + tid] = z4;
    return;
  }
  const int flat = (bb - 321) * 256 + tid;   // 0..24575
  const int m = flat >= 12288;
  const int idx = flat - (m ? 12288 : 0);
  const float* src = m ? c3w : c2w;
  ushort* dst = m ? cwt3 : cwt2;
  const int o = idx / 192, rem = idx - o * 192;
  const int kk = rem >> 6, c = rem & 63;
  dst[idx] = f2bf(src[o * 192 + c * 3 + kk]);
}

// ---------------------------------------------------------------------------
// Stage 1: EdgeConv via count-matrix (R11). One block per graph.
// ---------------------------------------------------------------------------
__global__ __launch_bounds__(256) void k_edge(
    const float* __restrict__ x, const int* __restrict__ ei,
    const float* __restrict__ w1, const float* __restrict__ b1,
    const float* __restrict__ w2, const float* __restrict__ b2,
    ushort* __restrict__ out0, float* __restrict__ stats1)
{
  __shared__ float xs[64];
  __shared__ int   Mc[64][65];          // padded: stride 65 -> conflict-free
  __shared__ float aggC[64][8];
  __shared__ float w1s[8], b1s[4];
  __shared__ float w2s[256], b2s[64];
  __shared__ float rs[4][64], rss[4][64];
  const int tid = threadIdx.x;
  const int b = blockIdx.x;

  if (tid < 8) w1s[tid] = w1[tid];
  if (tid < 4) b1s[tid] = b1[tid];
  if (tid < 64) { xs[tid] = x[(b << 6) + tid]; b2s[tid] = b2[tid]; }
  w2s[tid] = w2[tid];
  for (int i = tid; i < 64 * 65; i += 256) ((int*)Mc)[i] = 0;
  __syncthreads();

  const int e0 = b * EPG;
  const int4 s4 = ((const int4*)(ei + e0))[tid];
  const int4 d4 = ((const int4*)(ei + NEDGE + e0))[tid];
  atomicAdd(&Mc[d4.x & 63][s4.x & 63], 1);
  atomicAdd(&Mc[d4.y & 63][s4.y & 63], 1);
  atomicAdd(&Mc[d4.z & 63][s4.z & 63], 1);
  atomicAdd(&Mc[d4.w & 63][s4.w & 63], 1);
  __syncthreads();

  // per (n,j): agg = sum_m Mc[n][m] * relu(w1[j]*x_n + w1[4+j]*(x_m-x_n) + b1[j])
  {
    const int n = tid & 63, j = tid >> 6;
    const float xn = xs[n];
    const float bj = w1s[4 + j];
    const float alpha = fmaf(xn, w1s[j] - bj, b1s[j]);
    float acc = 0.f;
    int dg = 0;
#pragma unroll 8
    for (int m = 0; m < 64; ++m) {
      const int c = Mc[n][m];
      const float h = fmaxf(fmaf(bj, xs[m], alpha), 0.f);
      acc += (float)c * h;
      dg += c;
    }
    aggC[n][j] = acc;
    if (j == 0) aggC[n][4] = (float)dg;
  }
  __syncthreads();

  const int c = tid & 63, qq = tid >> 6;
  const float wc0 = w2s[c], wc1 = w2s[64 + c], wc2 = w2s[128 + c], wc3 = w2s[192 + c];
  const float b2c = b2s[c];
  float s = 0.f, ss = 0.f;
  for (int n = qq; n < 64; n += 4) {
    const float4 a = *(const float4*)&aggC[n][0];
    const float dg = aggC[n][4];
    float v = a.x * wc0 + a.y * wc1 + a.z * wc2 + a.w * wc3 + dg * b2c;
    out0[(size_t)(((b << 6) + n) << 6) + c] = f2bf(v);
    s += v; ss += v * v;
  }
  rs[qq][c] = s; rss[qq][c] = ss;
  __syncthreads();
  if (tid < 64) {
    float* dst = stats1 + ((b & (REP - 1)) << 7);
    atomicAdd(&dst[tid], rs[0][tid] + rs[1][tid] + rs[2][tid] + rs[3][tid]);
    atomicAdd(&dst[64 + tid], rss[0][tid] + rss[1][tid] + rss[2][tid] + rss[3][tid]);
  }
}

// ---------------------------------------------------------------------------
// k_convm: bf16 in [l][c] -> BN(replica-sum stats)+ReLU -> Yt bf16 -> conv1d
// as MFMA GEMM (M=o, N=l, K=192) -> bf16 out [l][o] + fp32 replica stats.
// A-operand (conv weights) direct from global cwt (R12).
// ---------------------------------------------------------------------------
__global__ __launch_bounds__(256) void k_convm(
    const ushort* __restrict__ in,           // [1024][64 l][64 c] bf16
    const float* __restrict__ stats_in,      // [REP][128]
    const float* __restrict__ gamma, const float* __restrict__ beta,
    const ushort* __restrict__ cwt, const float* __restrict__ cb,
    ushort* __restrict__ out,                // [1024][64 l][64 o] bf16
    float* __restrict__ stats_out)           // [REP][128]
{
  __shared__ ushort Yt[66][72];
  __shared__ float aco[64], bco[64], cbs[64];
  __shared__ float ldsS[64], ldsSS[64];
  const int tid = threadIdx.x;
  const int b = blockIdx.x;

  if (tid < 64) {
    float sm = 0.f, sq = 0.f;
#pragma unroll 8
    for (int r = 0; r < REP; ++r) {
      sm += stats_in[(r << 7) + tid];
      sq += stats_in[(r << 7) + 64 + tid];
    }
    const float mean = sm * (1.0f / CNTF);
    const float var = sq * (1.0f / CNTF) - mean * mean;
    const float a = gamma[tid] * rsqrtf(var + EPSV);
    aco[tid] = a;
    bco[tid] = beta[tid] - mean * a;
    cbs[tid] = cb[tid];
    Yt[0][tid] = 0;
    Yt[65][tid] = 0;
  }
  __syncthreads();

  const size_t base = (size_t)b << 12;
  {
    const int lr = tid >> 2, p = (tid & 3) << 4;
    const ushort8 r0 = *(const ushort8*)&in[base + (lr << 6) + p];
    const ushort8 r1 = *(const ushort8*)&in[base + (lr << 6) + p + 8];
    ushort tmp[16];
#pragma unroll
    for (int j = 0; j < 8; ++j)
      tmp[j] = f2bf(fmaxf(fmaf(aco[p + j], bf2f(r0[j]), bco[p + j]), 0.f));
#pragma unroll
    for (int j = 0; j < 8; ++j)
      tmp[8 + j] = f2bf(fmaxf(fmaf(aco[p + 8 + j], bf2f(r1[j]), bco[p + 8 + j]), 0.f));
    *(ushort8*)&Yt[lr + 1][p] = *(ushort8*)&tmp[0];
    *(ushort8*)&Yt[lr + 1][p + 8] = *(ushort8*)&tmp[8];
  }
  __syncthreads();

  const int lane = tid & 63, w = tid >> 6;
  const int lm = lane & 15, q = lane >> 4;
  const ushort* arow = cwt + ((w << 4) + lm) * 192;   // this lane's A-row
  f32x4 acc[4];
#pragma unroll
  for (int nt = 0; nt < 4; ++nt) acc[nt] = (f32x4){0.f, 0.f, 0.f, 0.f};

#pragma unroll
  for (int kk = 0; kk < 3; ++kk) {
#pragma unroll
    for (int ks = 0; ks < 2; ++ks) {
      const short8 af = *(const short8*)&arow[(kk << 6) + (ks << 5) + (q << 3)];
#pragma unroll
      for (int nt = 0; nt < 4; ++nt) {
        const short8 bfr = *(const short8*)&Yt[(nt << 4) + lm + kk][(ks << 5) + (q << 3)];
        acc[nt] = __builtin_amdgcn_mfma_f32_16x16x32_bf16(af, bfr, acc[nt], 0, 0, 0);
      }
    }
  }

  const int obase = (w << 4) + (q << 2);
  const float4 cb4 = *(const float4*)&cbs[obase];
  float s[4] = {0.f, 0.f, 0.f, 0.f}, ss[4] = {0.f, 0.f, 0.f, 0.f};
#pragma unroll
  for (int nt = 0; nt < 4; ++nt) {
    const int l = (nt << 4) + lm;
    float4 v = make_float4(acc[nt][0] + cb4.x, acc[nt][1] + cb4.y,
                           acc[nt][2] + cb4.z, acc[nt][3] + cb4.w);
    *(ushort4*)&out[base + (l << 6) + obase] =
        make_ushort4(f2bf(v.x), f2bf(v.y), f2bf(v.z), f2bf(v.w));
    s[0] += v.x; ss[0] += v.x * v.x;
    s[1] += v.y; ss[1] += v.y * v.y;
    s[2] += v.z; ss[2] += v.z * v.z;
    s[3] += v.w; ss[3] += v.w * v.w;
  }
#pragma unroll
  for (int i = 0; i < 4; ++i) {
#pragma unroll
    for (int off = 1; off < 16; off <<= 1) {
      s[i] += __shfl_xor(s[i], off);
      ss[i] += __shfl_xor(ss[i], off);
    }
    if (lm == 0) { ldsS[obase + i] = s[i]; ldsSS[obase + i] = ss[i]; }
  }
  __syncthreads();
  if (tid < 64) {
    float* dst = stats_out + ((b & (REP - 1)) << 7);
    atomicAdd(&dst[tid], ldsS[tid]);
    atomicAdd(&dst[64 + tid], ldsSS[tid]);
  }
}

// ---------------------------------------------------------------------------
// k_mlp1: h1part[bz] = (BN3+ReLU(z3)) @ wm1 partial, bf16 MFMA 16x16x32.
// B-operand (wbf1t fragments) DIRECT from global (L2-hot, wave-broadcast,
// 16-block panel reuse). Ys (BN3+ReLU activations) stays in LDS.
// Grid (16 Mtiles, 2 Ntiles of 128, 8 Ksplits). acc[8] per wave.
// ---------------------------------------------------------------------------
__global__ __launch_bounds__(256) void k_mlp1(
    const ushort* __restrict__ z3, const float* __restrict__ stats3,
    const float* __restrict__ g3, const float* __restrict__ be3,
    const ushort* __restrict__ wbf1t, float* __restrict__ h1part)
{
  __shared__ ushort Ys[64][72];
  __shared__ float a3s[64], b3s[64];
  const int tid = threadIdx.x;
  const int bx = blockIdx.x, by = blockIdx.y, bz = blockIdx.z;

  if (tid < 64) {
    float sm = 0.f, sq = 0.f;
#pragma unroll 8
    for (int r = 0; r < REP; ++r) {
      sm += stats3[(r << 7) + tid];
      sq += stats3[(r << 7) + 64 + tid];
    }
    const float mean = sm * (1.0f / CNTF);
    const float var = sq * (1.0f / CNTF) - mean * mean;
    const float a = g3[tid] * rsqrtf(var + EPSV);
    a3s[tid] = a;
    b3s[tid] = be3[tid] - mean * a;
  }
  __syncthreads();

  const int lane = tid & 63, w = tid >> 6;
  const int lm = lane & 15, q = lane >> 4;
  const int gy = tid >> 2, py = (tid & 3) << 4;   // Ys staging: graph, k-part
  const int g0 = bx << 6, n0 = by << 7;

  f32x4 acc[8];
#pragma unroll
  for (int nt = 0; nt < 8; ++nt) acc[nt] = (f32x4){0.f, 0.f, 0.f, 0.f};

  const size_t ybase = ((size_t)(g0 + gy) << 12);

#pragma unroll 1
  for (int ck = 0; ck < 8; ++ck) {
    const int kc = (bz << 9) + (ck << 6);
    if (ck) __syncthreads();
    // --- stage Ys: BN3+ReLU on bf16 z3 (channel = within-chunk index)
    {
      const ushort* src = z3 + ybase + kc + py;
      const ushort8 r0 = *(const ushort8*)src;
      const ushort8 r1 = *(const ushort8*)(src + 8);
      ushort tmp[16];
#pragma unroll
      for (int j = 0; j < 8; ++j)
        tmp[j] = f2bf(fmaxf(fmaf(a3s[py + j], bf2f(r0[j]), b3s[py + j]), 0.f));
#pragma unroll
      for (int j = 0; j < 8; ++j)
        tmp[8 + j] = f2bf(fmaxf(fmaf(a3s[py + 8 + j], bf2f(r1[j]), b3s[py + 8 + j]), 0.f));
      *(ushort8*)&Ys[gy][py] = *(ushort8*)&tmp[0];
      *(ushort8*)&Ys[gy][py + 8] = *(ushort8*)&tmp[8];
    }
    __syncthreads();
    // B-operand direct from chunk-major wbf1t: row n0+(nt<<4)+lm, 64-k chunk
    const ushort* wrow = wbf1t + ((size_t)((bz << 3) + ck) << 14) + ((size_t)n0 << 6);
#pragma unroll
    for (int ks = 0; ks < 2; ++ks) {
      const short8 af = *(const short8*)&Ys[(w << 4) + lm][(ks << 5) + (q << 3)];
#pragma unroll
      for (int nt = 0; nt < 8; ++nt) {
        const short8 bfr = *(const short8*)&wrow[(((nt << 4) + lm) << 6) + (ks << 5) + (q << 3)];
        acc[nt] = __builtin_amdgcn_mfma_f32_16x16x32_bf16(af, bfr, acc[nt], 0, 0, 0);
      }
    }
  }

  float* dst0 = h1part + ((size_t)bz << 18);
  const int gout = g0 + (w << 4) + (q << 2);
#pragma unroll
  for (int nt = 0; nt < 8; ++nt) {
    const int col = n0 + (nt << 4) + lm;
#pragma unroll
    for (int i = 0; i < 4; ++i)
      dst0[((size_t)(gout + i) << 8) + col] = acc[nt][i];
  }
}

// ---------------------------------------------------------------------------
// k_tail: h1 = relu(sum_bz h1part + bm1) -> h2 -> h3 -> logits -> logsoftmax.
// 64 blocks x 16 graphs. (unchanged)
// ---------------------------------------------------------------------------
__global__ __launch_bounds__(256) void k_tail(
    const float* __restrict__ h1part, const float* __restrict__ bm1,
    const ushort* __restrict__ wbf2t, const float* __restrict__ bm2,
    const ushort* __restrict__ wbf3t, const float* __restrict__ bm3,
    const ushort* __restrict__ wptbf, const float* __restrict__ bp,
    float* __restrict__ out)
{
  __shared__ ushort Ws[256][72];
  __shared__ ushort h1s[16][264];
  __shared__ ushort h2s[16][264];
  ushort* wpt = &Ws[0][0];
  const int tid = threadIdx.x;
  const int g0 = blockIdx.x << 4;
  const int lane = tid & 63, w = tid >> 6;
  const int lm = lane & 15, q = lane >> 4;
  const int gr = q << 2;

  {
    const int r = tid >> 4, c0 = (tid & 15) << 4;
    const float* srcb = h1part + ((size_t)(g0 + r) << 8) + c0;
#pragma unroll
    for (int i = 0; i < 4; ++i) {
      float4 vs = *(const float4*)(bm1 + c0 + (i << 2));
#pragma unroll
      for (int bz = 0; bz < 8; ++bz) {
        const float4 p = *(const float4*)(srcb + ((size_t)bz << 18) + (i << 2));
        vs.x += p.x; vs.y += p.y; vs.z += p.z; vs.w += p.w;
      }
      *(ushort4*)&h1s[r][c0 + (i << 2)] = make_ushort4(
          f2bf(fmaxf(vs.x, 0.f)), f2bf(fmaxf(vs.y, 0.f)),
          f2bf(fmaxf(vs.z, 0.f)), f2bf(fmaxf(vs.w, 0.f)));
    }
  }

  // ---- GEMM2
  f32x4 acc[4];
#pragma unroll
  for (int nt = 0; nt < 4; ++nt) acc[nt] = (f32x4){0.f, 0.f, 0.f, 0.f};
#pragma unroll 1
  for (int ck = 0; ck < 4; ++ck) {
    __syncthreads();
    {
      const ushort8* gw = (const ushort8*)(wbf2t + (ck << 14));
#pragma unroll
      for (int i = 0; i < 8; ++i) {
        const int e8 = (i << 8) + tid;
        const int n = e8 >> 3, kk = (e8 & 7) << 3;
        *(ushort8*)&Ws[n][kk] = gw[e8];
      }
    }
    __syncthreads();
#pragma unroll
    for (int ks = 0; ks < 2; ++ks) {
      const short8 af = *(const short8*)&h1s[lm][(ck << 6) + (ks << 5) + (q << 3)];
#pragma unroll
      for (int nt = 0; nt < 4; ++nt) {
        const short8 bfr = *(const short8*)&Ws[(w << 6) + (nt << 4) + lm][(ks << 5) + (q << 3)];
        acc[nt] = __builtin_amdgcn_mfma_f32_16x16x32_bf16(af, bfr, acc[nt], 0, 0, 0);
      }
    }
  }
#pragma unroll
  for (int nt = 0; nt < 4; ++nt) {
    const int col = (w << 6) + (nt << 4) + lm;
    const float bv = bm2[col];
#pragma unroll
    for (int i = 0; i < 4; ++i)
      h2s[gr + i][col] = f2bf(fmaxf(acc[nt][i] + bv, 0.f));
  }

  // ---- GEMM3
  f32x4 acc2[4];
#pragma unroll
  for (int nt = 0; nt < 4; ++nt) acc2[nt] = (f32x4){0.f, 0.f, 0.f, 0.f};
#pragma unroll 1
  for (int ck = 0; ck < 4; ++ck) {
    __syncthreads();
    {
      const ushort8* gw = (const ushort8*)(wbf3t + (ck << 14));
#pragma unroll
      for (int i = 0; i < 8; ++i) {
        const int e8 = (i << 8) + tid;
        const int n = e8 >> 3, kk = (e8 & 7) << 3;
        *(ushort8*)&Ws[n][kk] = gw[e8];
      }
    }
    __syncthreads();
#pragma unroll
    for (int ks = 0; ks < 2; ++ks) {
      const short8 af = *(const short8*)&h2s[lm][(ck << 6) + (ks << 5) + (q << 3)];
#pragma unroll
      for (int nt = 0; nt < 4; ++nt) {
        const short8 bfr = *(const short8*)&Ws[(w << 6) + (nt << 4) + lm][(ks << 5) + (q << 3)];
        acc2[nt] = __builtin_amdgcn_mfma_f32_16x16x32_bf16(af, bfr, acc2[nt], 0, 0, 0);
      }
    }
  }

  __syncthreads();
  {
    const ushort8* gw = (const ushort8*)wptbf;
#pragma unroll
    for (int i = 0; i < 2; ++i) {
      const int e8 = (i << 8) + tid;
      const int flat = e8 << 3;
      const int a = flat >> 8, kk = flat & 255;
      *(ushort8*)&wpt[a * 264 + kk] = gw[e8];
    }
  }
#pragma unroll
  for (int nt = 0; nt < 4; ++nt) {
    const int col = (w << 6) + (nt << 4) + lm;
    const float bv = bm3[col];
#pragma unroll
    for (int i = 0; i < 4; ++i)
      h2s[gr + i][col] = f2bf(fmaxf(acc2[nt][i] + bv, 0.f));
  }
  __syncthreads();

  if (w == 0) {
    f32x4 lacc = (f32x4){0.f, 0.f, 0.f, 0.f};
#pragma unroll
    for (int ks = 0; ks < 8; ++ks) {
      const short8 af = *(const short8*)&h2s[lm][(ks << 5) + (q << 3)];
      const short8 bfr = *(const short8*)&wpt[lm * 264 + (ks << 5) + (q << 3)];
      lacc = __builtin_amdgcn_mfma_f32_16x16x32_bf16(af, bfr, lacc, 0, 0, 0);
    }
    const float bpv = bp[lm];
    float lg[4], mx[4], se[4];
#pragma unroll
    for (int i = 0; i < 4; ++i) {
      lg[i] = lacc[i] + bpv;
      float m = lg[i];
#pragma unroll
      for (int off = 1; off < 16; off <<= 1) m = fmaxf(m, __shfl_xor(m, off));
      mx[i] = m;
      float e = expf(lg[i] - m);
#pragma unroll
      for (int off = 1; off < 16; off <<= 1) e += __shfl_xor(e, off);
      se[i] = e;
    }
#pragma unroll
    for (int i = 0; i < 4; ++i)
      out[((g0 + gr + i) << 4) + lm] = (lg[i] - mx[i]) - logf(se[i]);
  }
}

// ---------------------------------------------------------------------------
extern "C" void kernel_launch(void* const* d_in, const int* in_sizes, int n_in,
                              void* d_out, int out_size, void* d_ws, size_t ws_size,
                              hipStream_t stream)
{
  const float* x   = (const float*)d_in[0];
  const int*   ei  = (const int*)d_in[1];
  const float* w1  = (const float*)d_in[2];
  const float* b1  = (const float*)d_in[3];
  const float* w2  = (const float*)d_in[4];
  const float* b2  = (const float*)d_in[5];
  const float* c2w = (const float*)d_in[6];
  const float* c2b = (const float*)d_in[7];
  const float* c3w = (const float*)d_in[8];
  const float* c3b = (const float*)d_in[9];
  const float* g1  = (const float*)d_in[10];
  const float* be1 = (const float*)d_in[11];
  const float* g2  = (const float*)d_in[12];
  const float* be2 = (const float*)d_in[13];
  const float* g3  = (const float*)d_in[14];
  const float* be3 = (const float*)d_in[15];
  const float* wm1 = (const float*)d_in[16];
  const float* bm1 = (const float*)d_in[17];
  const float* wm2 = (const float*)d_in[18];
  const float* bm2 = (const float*)d_in[19];
  const float* wm3 = (const float*)d_in[20];
  const float* bm3 = (const float*)d_in[21];
  const float* wp  = (const float*)d_in[22];
  const float* bp  = (const float*)d_in[23];

  char* ws = (char*)d_ws;
  ushort* ubuf0 = (ushort*)ws;                          // 8 MiB: out0 -> z3 (bf16)
  ushort* ubuf1 = (ushort*)(ws + ((size_t)8 << 20));    // 8 MiB: z2 (bf16)
  float*  h1part = (float*)(ws + ((size_t)16 << 20));   // 8 MiB fp32 partials
  ushort* wbf1t = (ushort*)(ws + ((size_t)24 << 20));   // 2 MiB bf16 wm1^T
  ushort* wbf2t = (ushort*)(ws + ((size_t)26 << 20));               // 128 KiB
  ushort* wbf3t = (ushort*)(ws + ((size_t)26 << 20) + (128 << 10)); // 128 KiB
  ushort* wptbf = (ushort*)(ws + ((size_t)26 << 20) + (256 << 10)); // 8 KiB
  float* stats = (float*)(ws + ((size_t)27 << 20));
  float* stats1 = stats;                  // [REP][128]
  float* stats2 = stats + REP * 128;
  float* stats3 = stats + 2 * REP * 128;
  ushort* cwt2 = (ushort*)d_out;          // d_out scratch, overwritten by k_tail
  ushort* cwt3 = (ushort*)d_out + 12288;

  k_prepw<<<dim3(418), dim3(256), 0, stream>>>(
      wm1, wm2, wm3, wp, c2w, c3w,
      wbf1t, wbf2t, wbf3t, wptbf, cwt2, cwt3, stats);
  k_edge<<<dim3(NB), dim3(256), 0, stream>>>(x, ei, w1, b1, w2, b2, ubuf0, stats1);
  k_convm<<<dim3(NB), dim3(256), 0, stream>>>(ubuf0, stats1, g1, be1, cwt2, c2b, ubuf1, stats2);
  k_convm<<<dim3(NB), dim3(256), 0, stream>>>(ubuf1, stats2, g2, be2, cwt3, c3b, ubuf0, stats3);
  k_mlp1<<<dim3(16, 2, 8), dim3(256), 0, stream>>>(ubuf0, stats3, g3, be3, wbf1t, h1part);
  k_tail<<<dim3(64), dim3(256), 0, stream>>>(h1part, bm1, wbf2t, bm2, wbf3t, bm3,
                                             wptbf, bp, (float*)d_out);
}

// Round 14
// 165.420 us; speedup vs baseline: 1.0992x; 1.0992x over previous
//
#include <hip/hip_runtime.h>
#include <cstdint>
#include <cstddef>

typedef __attribute__((ext_vector_type(8))) short short8;
typedef __attribute__((ext_vector_type(8))) unsigned short ushort8;
typedef __attribute__((ext_vector_type(4))) float f32x4;

#define EPSV 1e-5f
#define NB 1024
#define NEDGE 1048576
#define EPG 1024
#define CNTF 65536.0f
#define REP 32           // stats replica slots (contention spreading)

// ---------------------------------------------------------------------------
// R14: revert R13's mlp1 B-direct (regression +17us: direct B-fragments are
// SINGLE-USE per MFMA -> 16 L2-latency loads/ck on the MFMA dep chain; the
// convm direct-A works only because each A-row is register-reused x4).
// k_mlp1 restored to R12's staged version (champion 164.4us).
// ONE new change vs R12: k_tail widened 256 -> 512 threads (8 waves,
// 2 waves/SIMD on its 64 CUs): halves per-thread staging + GEMM ownership,
// doubles latency hiding across its serial barrier chain. Same 16-graph
// structure, same arithmetic.
// ---------------------------------------------------------------------------

__device__ __forceinline__ ushort f2bf(float f) {
  uint u = __float_as_uint(f);
  return (ushort)((u + 0x7FFFu + ((u >> 16) & 1u)) >> 16);
}
__device__ __forceinline__ float bf2f(ushort u) {
  return __uint_as_float((uint)u << 16);
}

// ---------------------------------------------------------------------------
// k_prepw: all weight preprocessing + stats zeroing in ONE kernel.
// ---------------------------------------------------------------------------
__global__ __launch_bounds__(256) void k_prepw(
    const float* __restrict__ wm1, const float* __restrict__ wm2,
    const float* __restrict__ wm3, const float* __restrict__ wp,
    const float* __restrict__ c2w, const float* __restrict__ c3w,
    ushort* __restrict__ wbf1t, ushort* __restrict__ wbf2t,
    ushort* __restrict__ wbf3t, ushort* __restrict__ wptbf,
    ushort* __restrict__ cwt2, ushort* __restrict__ cwt3,
    float* __restrict__ stats)
{
  __shared__ ushort T[64][72];
  const int tid = threadIdx.x;
  const int bb = blockIdx.x;

  if (bb < 256) {
    const int kc = bb >> 2, n0 = (bb & 3) << 6;
    const int kk = tid >> 2, np = (tid & 3) << 4;
    const float* srow = wm1 + (((size_t)(kk << 6) + kc) << 8) + n0 + np;
#pragma unroll
    for (int i = 0; i < 4; ++i) {
      const float4 v = *(const float4*)(srow + (i << 2));
      const int n = np + (i << 2);
      T[n + 0][kk] = f2bf(v.x); T[n + 1][kk] = f2bf(v.y);
      T[n + 2][kk] = f2bf(v.z); T[n + 3][kk] = f2bf(v.w);
    }
    __syncthreads();
    ushort* dst = wbf1t + ((size_t)kc << 14) + (n0 << 6);
    const int nl = tid >> 2, qk = (tid & 3) << 4;
    *(ushort8*)(dst + (nl << 6) + qk) = *(ushort8*)&T[nl][qk];
    *(ushort8*)(dst + (nl << 6) + qk + 8) = *(ushort8*)&T[nl][qk + 8];
    return;
  }
  if (bb < 320) {
    const int base = (((bb - 256) << 8) + tid) << 3;
    const int m = base >> 16;
    const int rem = base & 65535;
    const int kc = rem >> 14, within = rem & 16383;
    const int n = within >> 6, kk0 = within & 63;
    const float* src = m ? wm3 : wm2;
    ushort* dst = m ? wbf3t : wbf2t;
    ushort tmp[8];
#pragma unroll
    for (int j = 0; j < 8; ++j)
      tmp[j] = f2bf(src[(((kc << 6) | (kk0 + j)) << 8) + n]);
    *(ushort8*)&dst[rem] = *(ushort8*)&tmp[0];
    return;
  }
  if (bb == 320) {
    const int a = tid & 15, k0 = (tid >> 4) << 4;
    ushort tmp[16];
#pragma unroll
    for (int j = 0; j < 16; ++j) tmp[j] = f2bf(wp[((k0 + j) << 4) + a]);
    *(ushort8*)&wptbf[(a << 8) + k0] = *(ushort8*)&tmp[0];
    *(ushort8*)&wptbf[(a << 8) + k0 + 8] = *(ushort8*)&tmp[8];
    return;
  }
  if (bb == 417) {
    float4 z4 = make_float4(0.f, 0.f, 0.f, 0.f);
#pragma unroll
    for (int i = 0; i < 12; ++i) ((float4*)stats)[(i << 8) + tid] = z4;
    return;
  }
  const int flat = (bb - 321) * 256 + tid;   // 0..24575
  const int m = flat >= 12288;
  const int idx = flat - (m ? 12288 : 0);
  const float* src = m ? c3w : c2w;
  ushort* dst = m ? cwt3 : cwt2;
  const int o = idx / 192, rem = idx - o * 192;
  const int kk = rem >> 6, c = rem & 63;
  dst[idx] = f2bf(src[o * 192 + c * 3 + kk]);
}

// ---------------------------------------------------------------------------
// Stage 1: EdgeConv via count-matrix (R11). One block per graph.
// ---------------------------------------------------------------------------
__global__ __launch_bounds__(256) void k_edge(
    const float* __restrict__ x, const int* __restrict__ ei,
    const float* __restrict__ w1, const float* __restrict__ b1,
    const float* __restrict__ w2, const float* __restrict__ b2,
    ushort* __restrict__ out0, float* __restrict__ stats1)
{
  __shared__ float xs[64];
  __shared__ int   Mc[64][65];          // padded: stride 65 -> conflict-free
  __shared__ float aggC[64][8];
  __shared__ float w1s[8], b1s[4];
  __shared__ float w2s[256], b2s[64];
  __shared__ float rs[4][64], rss[4][64];
  const int tid = threadIdx.x;
  const int b = blockIdx.x;

  if (tid < 8) w1s[tid] = w1[tid];
  if (tid < 4) b1s[tid] = b1[tid];
  if (tid < 64) { xs[tid] = x[(b << 6) + tid]; b2s[tid] = b2[tid]; }
  w2s[tid] = w2[tid];
  for (int i = tid; i < 64 * 65; i += 256) ((int*)Mc)[i] = 0;
  __syncthreads();

  const int e0 = b * EPG;
  const int4 s4 = ((const int4*)(ei + e0))[tid];
  const int4 d4 = ((const int4*)(ei + NEDGE + e0))[tid];
  atomicAdd(&Mc[d4.x & 63][s4.x & 63], 1);
  atomicAdd(&Mc[d4.y & 63][s4.y & 63], 1);
  atomicAdd(&Mc[d4.z & 63][s4.z & 63], 1);
  atomicAdd(&Mc[d4.w & 63][s4.w & 63], 1);
  __syncthreads();

  // per (n,j): agg = sum_m Mc[n][m] * relu(w1[j]*x_n + w1[4+j]*(x_m-x_n) + b1[j])
  {
    const int n = tid & 63, j = tid >> 6;
    const float xn = xs[n];
    const float bj = w1s[4 + j];
    const float alpha = fmaf(xn, w1s[j] - bj, b1s[j]);
    float acc = 0.f;
    int dg = 0;
#pragma unroll 8
    for (int m = 0; m < 64; ++m) {
      const int c = Mc[n][m];
      const float h = fmaxf(fmaf(bj, xs[m], alpha), 0.f);
      acc += (float)c * h;
      dg += c;
    }
    aggC[n][j] = acc;
    if (j == 0) aggC[n][4] = (float)dg;
  }
  __syncthreads();

  const int c = tid & 63, qq = tid >> 6;
  const float wc0 = w2s[c], wc1 = w2s[64 + c], wc2 = w2s[128 + c], wc3 = w2s[192 + c];
  const float b2c = b2s[c];
  float s = 0.f, ss = 0.f;
  for (int n = qq; n < 64; n += 4) {
    const float4 a = *(const float4*)&aggC[n][0];
    const float dg = aggC[n][4];
    float v = a.x * wc0 + a.y * wc1 + a.z * wc2 + a.w * wc3 + dg * b2c;
    out0[(size_t)(((b << 6) + n) << 6) + c] = f2bf(v);
    s += v; ss += v * v;
  }
  rs[qq][c] = s; rss[qq][c] = ss;
  __syncthreads();
  if (tid < 64) {
    float* dst = stats1 + ((b & (REP - 1)) << 7);
    atomicAdd(&dst[tid], rs[0][tid] + rs[1][tid] + rs[2][tid] + rs[3][tid]);
    atomicAdd(&dst[64 + tid], rss[0][tid] + rss[1][tid] + rss[2][tid] + rss[3][tid]);
  }
}

// ---------------------------------------------------------------------------
// k_convm: BN + conv1d-as-MFMA; A-operand direct from global cwt (R12).
// ---------------------------------------------------------------------------
__global__ __launch_bounds__(256) void k_convm(
    const ushort* __restrict__ in,           // [1024][64 l][64 c] bf16
    const float* __restrict__ stats_in,      // [REP][128]
    const float* __restrict__ gamma, const float* __restrict__ beta,
    const ushort* __restrict__ cwt, const float* __restrict__ cb,
    ushort* __restrict__ out,                // [1024][64 l][64 o] bf16
    float* __restrict__ stats_out)           // [REP][128]
{
  __shared__ ushort Yt[66][72];
  __shared__ float aco[64], bco[64], cbs[64];
  __shared__ float ldsS[64], ldsSS[64];
  const int tid = threadIdx.x;
  const int b = blockIdx.x;

  if (tid < 64) {
    float sm = 0.f, sq = 0.f;
#pragma unroll 8
    for (int r = 0; r < REP; ++r) {
      sm += stats_in[(r << 7) + tid];
      sq += stats_in[(r << 7) + 64 + tid];
    }
    const float mean = sm * (1.0f / CNTF);
    const float var = sq * (1.0f / CNTF) - mean * mean;
    const float a = gamma[tid] * rsqrtf(var + EPSV);
    aco[tid] = a;
    bco[tid] = beta[tid] - mean * a;
    cbs[tid] = cb[tid];
    Yt[0][tid] = 0;
    Yt[65][tid] = 0;
  }
  __syncthreads();

  const size_t base = (size_t)b << 12;
  {
    const int lr = tid >> 2, p = (tid & 3) << 4;
    const ushort8 r0 = *(const ushort8*)&in[base + (lr << 6) + p];
    const ushort8 r1 = *(const ushort8*)&in[base + (lr << 6) + p + 8];
    ushort tmp[16];
#pragma unroll
    for (int j = 0; j < 8; ++j)
      tmp[j] = f2bf(fmaxf(fmaf(aco[p + j], bf2f(r0[j]), bco[p + j]), 0.f));
#pragma unroll
    for (int j = 0; j < 8; ++j)
      tmp[8 + j] = f2bf(fmaxf(fmaf(aco[p + 8 + j], bf2f(r1[j]), bco[p + 8 + j]), 0.f));
    *(ushort8*)&Yt[lr + 1][p] = *(ushort8*)&tmp[0];
    *(ushort8*)&Yt[lr + 1][p + 8] = *(ushort8*)&tmp[8];
  }
  __syncthreads();

  const int lane = tid & 63, w = tid >> 6;
  const int lm = lane & 15, q = lane >> 4;
  const ushort* arow = cwt + ((w << 4) + lm) * 192;   // this lane's A-row
  f32x4 acc[4];
#pragma unroll
  for (int nt = 0; nt < 4; ++nt) acc[nt] = (f32x4){0.f, 0.f, 0.f, 0.f};

#pragma unroll
  for (int kk = 0; kk < 3; ++kk) {
#pragma unroll
    for (int ks = 0; ks < 2; ++ks) {
      const short8 af = *(const short8*)&arow[(kk << 6) + (ks << 5) + (q << 3)];
#pragma unroll
      for (int nt = 0; nt < 4; ++nt) {
        const short8 bfr = *(const short8*)&Yt[(nt << 4) + lm + kk][(ks << 5) + (q << 3)];
        acc[nt] = __builtin_amdgcn_mfma_f32_16x16x32_bf16(af, bfr, acc[nt], 0, 0, 0);
      }
    }
  }

  const int obase = (w << 4) + (q << 2);
  const float4 cb4 = *(const float4*)&cbs[obase];
  float s[4] = {0.f, 0.f, 0.f, 0.f}, ss[4] = {0.f, 0.f, 0.f, 0.f};
#pragma unroll
  for (int nt = 0; nt < 4; ++nt) {
    const int l = (nt << 4) + lm;
    float4 v = make_float4(acc[nt][0] + cb4.x, acc[nt][1] + cb4.y,
                           acc[nt][2] + cb4.z, acc[nt][3] + cb4.w);
    *(ushort4*)&out[base + (l << 6) + obase] =
        make_ushort4(f2bf(v.x), f2bf(v.y), f2bf(v.z), f2bf(v.w));
    s[0] += v.x; ss[0] += v.x * v.x;
    s[1] += v.y; ss[1] += v.y * v.y;
    s[2] += v.z; ss[2] += v.z * v.z;
    s[3] += v.w; ss[3] += v.w * v.w;
  }
#pragma unroll
  for (int i = 0; i < 4; ++i) {
#pragma unroll
    for (int off = 1; off < 16; off <<= 1) {
      s[i] += __shfl_xor(s[i], off);
      ss[i] += __shfl_xor(ss[i], off);
    }
    if (lm == 0) { ldsS[obase + i] = s[i]; ldsSS[obase + i] = ss[i]; }
  }
  __syncthreads();
  if (tid < 64) {
    float* dst = stats_out + ((b & (REP - 1)) << 7);
    atomicAdd(&dst[tid], ldsS[tid]);
    atomicAdd(&dst[64 + tid], ldsSS[tid]);
  }
}

// ---------------------------------------------------------------------------
// k_mlp1 (R12 staged version, reverted from R13): Ys + Ws staged in LDS.
// Grid (16 Mtiles, 2 Ntiles of 128, 8 Ksplits). acc[8] per wave.
// ---------------------------------------------------------------------------
__global__ __launch_bounds__(256) void k_mlp1(
    const ushort* __restrict__ z3, const float* __restrict__ stats3,
    const float* __restrict__ g3, const float* __restrict__ be3,
    const ushort* __restrict__ wbf1t, float* __restrict__ h1part)
{
  __shared__ ushort Ys[64][72];
  __shared__ ushort Ws[128][72];
  __shared__ float a3s[64], b3s[64];
  const int tid = threadIdx.x;
  const int bx = blockIdx.x, by = blockIdx.y, bz = blockIdx.z;

  if (tid < 64) {
    float sm = 0.f, sq = 0.f;
#pragma unroll 8
    for (int r = 0; r < REP; ++r) {
      sm += stats3[(r << 7) + tid];
      sq += stats3[(r << 7) + 64 + tid];
    }
    const float mean = sm * (1.0f / CNTF);
    const float var = sq * (1.0f / CNTF) - mean * mean;
    const float a = g3[tid] * rsqrtf(var + EPSV);
    a3s[tid] = a;
    b3s[tid] = be3[tid] - mean * a;
  }
  __syncthreads();

  const int lane = tid & 63, w = tid >> 6;
  const int lm = lane & 15, q = lane >> 4;
  const int gy = tid >> 2, py = (tid & 3) << 4;   // Ys staging: graph, k-part
  const int nn = tid >> 1, pp = (tid & 1) << 2;   // Ws staging: n-row, short8-part
  const int g0 = bx << 6, n0 = by << 7;

  f32x4 acc[8];
#pragma unroll
  for (int nt = 0; nt < 8; ++nt) acc[nt] = (f32x4){0.f, 0.f, 0.f, 0.f};

  const size_t ybase = ((size_t)(g0 + gy) << 12);

#pragma unroll 1
  for (int ck = 0; ck < 8; ++ck) {
    const int kc = (bz << 9) + (ck << 6);
    if (ck) __syncthreads();
    // --- stage Ys: BN3+ReLU on bf16 z3 (channel = within-chunk index)
    {
      const ushort* src = z3 + ybase + kc + py;
      const ushort8 r0 = *(const ushort8*)src;
      const ushort8 r1 = *(const ushort8*)(src + 8);
      ushort tmp[16];
#pragma unroll
      for (int j = 0; j < 8; ++j)
        tmp[j] = f2bf(fmaxf(fmaf(a3s[py + j], bf2f(r0[j]), b3s[py + j]), 0.f));
#pragma unroll
      for (int j = 0; j < 8; ++j)
        tmp[8 + j] = f2bf(fmaxf(fmaf(a3s[py + 8 + j], bf2f(r1[j]), b3s[py + 8 + j]), 0.f));
      *(ushort8*)&Ys[gy][py] = *(ushort8*)&tmp[0];
      *(ushort8*)&Ys[gy][py + 8] = *(ushort8*)&tmp[8];
    }
    // --- stage Ws: straight copies from chunk-major wbf1t
    {
      const ushort8* gw = (const ushort8*)(wbf1t + ((size_t)((bz << 3) + ck) << 14) + (n0 << 6));
#pragma unroll
      for (int i = 0; i < 4; ++i)
        *(ushort8*)&Ws[nn][(pp + i) << 3] = gw[(nn << 3) + pp + i];
    }
    __syncthreads();
#pragma unroll
    for (int ks = 0; ks < 2; ++ks) {
      const short8 af = *(const short8*)&Ys[(w << 4) + lm][(ks << 5) + (q << 3)];
#pragma unroll
      for (int nt = 0; nt < 8; ++nt) {
        const short8 bfr = *(const short8*)&Ws[(nt << 4) + lm][(ks << 5) + (q << 3)];
        acc[nt] = __builtin_amdgcn_mfma_f32_16x16x32_bf16(af, bfr, acc[nt], 0, 0, 0);
      }
    }
  }

  float* dst0 = h1part + ((size_t)bz << 18);
  const int gout = g0 + (w << 4) + (q << 2);
#pragma unroll
  for (int nt = 0; nt < 8; ++nt) {
    const int col = n0 + (nt << 4) + lm;
#pragma unroll
    for (int i = 0; i < 4; ++i)
      dst0[((size_t)(gout + i) << 8) + col] = acc[nt][i];
  }
}

// ---------------------------------------------------------------------------
// k_tail: 64 blocks x 512 threads (8 waves). Each wave owns 32 N-columns
// (nt<2); staging split over 512 threads. Same 16-graph structure and
// arithmetic as the 256-thread version.
// ---------------------------------------------------------------------------
__global__ __launch_bounds__(512) void k_tail(
    const float* __restrict__ h1part, const float* __restrict__ bm1,
    const ushort* __restrict__ wbf2t, const float* __restrict__ bm2,
    const ushort* __restrict__ wbf3t, const float* __restrict__ bm3,
    const ushort* __restrict__ wptbf, const float* __restrict__ bp,
    float* __restrict__ out)
{
  __shared__ ushort Ws[256][72];
  __shared__ ushort h1s[16][264];
  __shared__ ushort h2s[16][264];
  ushort* wpt = &Ws[0][0];
  const int tid = threadIdx.x;
  const int g0 = blockIdx.x << 4;
  const int lane = tid & 63, w = tid >> 6;      // 8 waves
  const int lm = lane & 15, q = lane >> 4;
  const int gr = q << 2;

  {
    const int r = tid >> 5, c0 = (tid & 31) << 3;     // 16 rows x 256 cols / 512 thr
    const float* srcb = h1part + ((size_t)(g0 + r) << 8) + c0;
#pragma unroll
    for (int i = 0; i < 2; ++i) {
      float4 vs = *(const float4*)(bm1 + c0 + (i << 2));
#pragma unroll
      for (int bz = 0; bz < 8; ++bz) {
        const float4 p = *(const float4*)(srcb + ((size_t)bz << 18) + (i << 2));
        vs.x += p.x; vs.y += p.y; vs.z += p.z; vs.w += p.w;
      }
      *(ushort4*)&h1s[r][c0 + (i << 2)] = make_ushort4(
          f2bf(fmaxf(vs.x, 0.f)), f2bf(fmaxf(vs.y, 0.f)),
          f2bf(fmaxf(vs.z, 0.f)), f2bf(fmaxf(vs.w, 0.f)));
    }
  }

  // ---- GEMM2 (each wave: 32 cols, nt<2)
  f32x4 acc[2];
#pragma unroll
  for (int nt = 0; nt < 2; ++nt) acc[nt] = (f32x4){0.f, 0.f, 0.f, 0.f};
#pragma unroll 1
  for (int ck = 0; ck < 4; ++ck) {
    __syncthreads();
    {
      const ushort8* gw = (const ushort8*)(wbf2t + (ck << 14));
#pragma unroll
      for (int i = 0; i < 4; ++i) {
        const int e8 = (i << 9) + tid;
        const int n = e8 >> 3, kk = (e8 & 7) << 3;
        *(ushort8*)&Ws[n][kk] = gw[e8];
      }
    }
    __syncthreads();
#pragma unroll
    for (int ks = 0; ks < 2; ++ks) {
      const short8 af = *(const short8*)&h1s[lm][(ck << 6) + (ks << 5) + (q << 3)];
#pragma unroll
      for (int nt = 0; nt < 2; ++nt) {
        const short8 bfr = *(const short8*)&Ws[(w << 5) + (nt << 4) + lm][(ks << 5) + (q << 3)];
        acc[nt] = __builtin_amdgcn_mfma_f32_16x16x32_bf16(af, bfr, acc[nt], 0, 0, 0);
      }
    }
  }
#pragma unroll
  for (int nt = 0; nt < 2; ++nt) {
    const int col = (w << 5) + (nt << 4) + lm;
    const float bv = bm2[col];
#pragma unroll
    for (int i = 0; i < 4; ++i)
      h2s[gr + i][col] = f2bf(fmaxf(acc[nt][i] + bv, 0.f));
  }

  // ---- GEMM3
  f32x4 acc2[2];
#pragma unroll
  for (int nt = 0; nt < 2; ++nt) acc2[nt] = (f32x4){0.f, 0.f, 0.f, 0.f};
#pragma unroll 1
  for (int ck = 0; ck < 4; ++ck) {
    __syncthreads();
    {
      const ushort8* gw = (const ushort8*)(wbf3t + (ck << 14));
#pragma unroll
      for (int i = 0; i < 4; ++i) {
        const int e8 = (i << 9) + tid;
        const int n = e8 >> 3, kk = (e8 & 7) << 3;
        *(ushort8*)&Ws[n][kk] = gw[e8];
      }
    }
    __syncthreads();
#pragma unroll
    for (int ks = 0; ks < 2; ++ks) {
      const short8 af = *(const short8*)&h2s[lm][(ck << 6) + (ks << 5) + (q << 3)];
#pragma unroll
      for (int nt = 0; nt < 2; ++nt) {
        const short8 bfr = *(const short8*)&Ws[(w << 5) + (nt << 4) + lm][(ks << 5) + (q << 3)];
        acc2[nt] = __builtin_amdgcn_mfma_f32_16x16x32_bf16(af, bfr, acc2[nt], 0, 0, 0);
      }
    }
  }

  __syncthreads();
  {
    const ushort8* gw = (const ushort8*)wptbf;
    const int e8 = tid;                         // 512 ushort8 = whole wpt
    const int flat = e8 << 3;
    const int a = flat >> 8, kk = flat & 255;
    *(ushort8*)&wpt[a * 264 + kk] = gw[e8];
  }
#pragma unroll
  for (int nt = 0; nt < 2; ++nt) {
    const int col = (w << 5) + (nt << 4) + lm;
    const float bv = bm3[col];
#pragma unroll
    for (int i = 0; i < 4; ++i)
      h2s[gr + i][col] = f2bf(fmaxf(acc2[nt][i] + bv, 0.f));
  }
  __syncthreads();

  if (w == 0) {
    f32x4 lacc = (f32x4){0.f, 0.f, 0.f, 0.f};
#pragma unroll
    for (int ks = 0; ks < 8; ++ks) {
      const short8 af = *(const short8*)&h2s[lm][(ks << 5) + (q << 3)];
      const short8 bfr = *(const short8*)&wpt[lm * 264 + (ks << 5) + (q << 3)];
      lacc = __builtin_amdgcn_mfma_f32_16x16x32_bf16(af, bfr, lacc, 0, 0, 0);
    }
    const float bpv = bp[lm];
    float lg[4], mx[4], se[4];
#pragma unroll
    for (int i = 0; i < 4; ++i) {
      lg[i] = lacc[i] + bpv;
      float m = lg[i];
#pragma unroll
      for (int off = 1; off < 16; off <<= 1) m = fmaxf(m, __shfl_xor(m, off));
      mx[i] = m;
      float e = expf(lg[i] - m);
#pragma unroll
      for (int off = 1; off < 16; off <<= 1) e += __shfl_xor(e, off);
      se[i] = e;
    }
#pragma unroll
    for (int i = 0; i < 4; ++i)
      out[((g0 + gr + i) << 4) + lm] = (lg[i] - mx[i]) - logf(se[i]);
  }
}

// ---------------------------------------------------------------------------
extern "C" void kernel_launch(void* const* d_in, const int* in_sizes, int n_in,
                              void* d_out, int out_size, void* d_ws, size_t ws_size,
                              hipStream_t stream)
{
  const float* x   = (const float*)d_in[0];
  const int*   ei  = (const int*)d_in[1];
  const float* w1  = (const float*)d_in[2];
  const float* b1  = (const float*)d_in[3];
  const float* w2  = (const float*)d_in[4];
  const float* b2  = (const float*)d_in[5];
  const float* c2w = (const float*)d_in[6];
  const float* c2b = (const float*)d_in[7];
  const float* c3w = (const float*)d_in[8];
  const float* c3b = (const float*)d_in[9];
  const float* g1  = (const float*)d_in[10];
  const float* be1 = (const float*)d_in[11];
  const float* g2  = (const float*)d_in[12];
  const float* be2 = (const float*)d_in[13];
  const float* g3  = (const float*)d_in[14];
  const float* be3 = (const float*)d_in[15];
  const float* wm1 = (const float*)d_in[16];
  const float* bm1 = (const float*)d_in[17];
  const float* wm2 = (const float*)d_in[18];
  const float* bm2 = (const float*)d_in[19];
  const float* wm3 = (const float*)d_in[20];
  const float* bm3 = (const float*)d_in[21];
  const float* wp  = (const float*)d_in[22];
  const float* bp  = (const float*)d_in[23];

  char* ws = (char*)d_ws;
  ushort* ubuf0 = (ushort*)ws;                          // 8 MiB: out0 -> z3 (bf16)
  ushort* ubuf1 = (ushort*)(ws + ((size_t)8 << 20));    // 8 MiB: z2 (bf16)
  float*  h1part = (float*)(ws + ((size_t)16 << 20));   // 8 MiB fp32 partials
  ushort* wbf1t = (ushort*)(ws + ((size_t)24 << 20));   // 2 MiB bf16 wm1^T
  ushort* wbf2t = (ushort*)(ws + ((size_t)26 << 20));               // 128 KiB
  ushort* wbf3t = (ushort*)(ws + ((size_t)26 << 20) + (128 << 10)); // 128 KiB
  ushort* wptbf = (ushort*)(ws + ((size_t)26 << 20) + (256 << 10)); // 8 KiB
  float* stats = (float*)(ws + ((size_t)27 << 20));
  float* stats1 = stats;                  // [REP][128]
  float* stats2 = stats + REP * 128;
  float* stats3 = stats + 2 * REP * 128;
  ushort* cwt2 = (ushort*)d_out;          // d_out scratch, overwritten by k_tail
  ushort* cwt3 = (ushort*)d_out + 12288;

  k_prepw<<<dim3(418), dim3(256), 0, stream>>>(
      wm1, wm2, wm3, wp, c2w, c3w,
      wbf1t, wbf2t, wbf3t, wptbf, cwt2, cwt3, stats);
  k_edge<<<dim3(NB), dim3(256), 0, stream>>>(x, ei, w1, b1, w2, b2, ubuf0, stats1);
  k_convm<<<dim3(NB), dim3(256), 0, stream>>>(ubuf0, stats1, g1, be1, cwt2, c2b, ubuf1, stats2);
  k_convm<<<dim3(NB), dim3(256), 0, stream>>>(ubuf1, stats2, g2, be2, cwt3, c3b, ubuf0, stats3);
  k_mlp1<<<dim3(16, 2, 8), dim3(256), 0, stream>>>(ubuf0, stats3, g3, be3, wbf1t, h1part);
  k_tail<<<dim3(64), dim3(512), 0, stream>>>(h1part, bm1, wbf2t, bm2, wbf3t, bm3,
                                             wptbf, bp, (float*)d_out);
}

// Round 15
// 157.833 us; speedup vs baseline: 1.1521x; 1.0481x over previous
//
#include <hip/hip_runtime.h>
#include <cstdint>
#include <cstddef>

typedef __attribute__((ext_vector_type(8))) short short8;
typedef __attribute__((ext_vector_type(8))) unsigned short ushort8;
typedef __attribute__((ext_vector_type(4))) float f32x4;

#define EPSV 1e-5f
#define NB 1024
#define NEDGE 1048576
#define EPG 1024
#define CNTF 65536.0f
#define REP 32           // stats replica slots (contention spreading)

// ---------------------------------------------------------------------------
// R15: R12 champion (164.4us) with ONE change: k_mlp1 N-tile split 128 -> 64.
// Grid (16,2,8)=256 blocks (1/CU, 1 wave/SIMD — worst latency hiding) ->
// (16,4,8)=512 blocks (2/CU): two blocks per CU interleave staging/barrier
// stalls. Ws stays LDS-staged (R13 lesson: single-use MFMA operands must be
// staged; only register-reused operands may go direct). acc[8]->acc[4].
// Same arithmetic; k_tail reverted to the proven 256-thread champion form.
// ---------------------------------------------------------------------------

__device__ __forceinline__ ushort f2bf(float f) {
  uint u = __float_as_uint(f);
  return (ushort)((u + 0x7FFFu + ((u >> 16) & 1u)) >> 16);
}
__device__ __forceinline__ float bf2f(ushort u) {
  return __uint_as_float((uint)u << 16);
}

// ---------------------------------------------------------------------------
// k_prepw: all weight preprocessing + stats zeroing in ONE kernel.
// ---------------------------------------------------------------------------
__global__ __launch_bounds__(256) void k_prepw(
    const float* __restrict__ wm1, const float* __restrict__ wm2,
    const float* __restrict__ wm3, const float* __restrict__ wp,
    const float* __restrict__ c2w, const float* __restrict__ c3w,
    ushort* __restrict__ wbf1t, ushort* __restrict__ wbf2t,
    ushort* __restrict__ wbf3t, ushort* __restrict__ wptbf,
    ushort* __restrict__ cwt2, ushort* __restrict__ cwt3,
    float* __restrict__ stats)
{
  __shared__ ushort T[64][72];
  const int tid = threadIdx.x;
  const int bb = blockIdx.x;

  if (bb < 256) {
    const int kc = bb >> 2, n0 = (bb & 3) << 6;
    const int kk = tid >> 2, np = (tid & 3) << 4;
    const float* srow = wm1 + (((size_t)(kk << 6) + kc) << 8) + n0 + np;
#pragma unroll
    for (int i = 0; i < 4; ++i) {
      const float4 v = *(const float4*)(srow + (i << 2));
      const int n = np + (i << 2);
      T[n + 0][kk] = f2bf(v.x); T[n + 1][kk] = f2bf(v.y);
      T[n + 2][kk] = f2bf(v.z); T[n + 3][kk] = f2bf(v.w);
    }
    __syncthreads();
    ushort* dst = wbf1t + ((size_t)kc << 14) + (n0 << 6);
    const int nl = tid >> 2, qk = (tid & 3) << 4;
    *(ushort8*)(dst + (nl << 6) + qk) = *(ushort8*)&T[nl][qk];
    *(ushort8*)(dst + (nl << 6) + qk + 8) = *(ushort8*)&T[nl][qk + 8];
    return;
  }
  if (bb < 320) {
    const int base = (((bb - 256) << 8) + tid) << 3;
    const int m = base >> 16;
    const int rem = base & 65535;
    const int kc = rem >> 14, within = rem & 16383;
    const int n = within >> 6, kk0 = within & 63;
    const float* src = m ? wm3 : wm2;
    ushort* dst = m ? wbf3t : wbf2t;
    ushort tmp[8];
#pragma unroll
    for (int j = 0; j < 8; ++j)
      tmp[j] = f2bf(src[(((kc << 6) | (kk0 + j)) << 8) + n]);
    *(ushort8*)&dst[rem] = *(ushort8*)&tmp[0];
    return;
  }
  if (bb == 320) {
    const int a = tid & 15, k0 = (tid >> 4) << 4;
    ushort tmp[16];
#pragma unroll
    for (int j = 0; j < 16; ++j) tmp[j] = f2bf(wp[((k0 + j) << 4) + a]);
    *(ushort8*)&wptbf[(a << 8) + k0] = *(ushort8*)&tmp[0];
    *(ushort8*)&wptbf[(a << 8) + k0 + 8] = *(ushort8*)&tmp[8];
    return;
  }
  if (bb == 417) {
    float4 z4 = make_float4(0.f, 0.f, 0.f, 0.f);
#pragma unroll
    for (int i = 0; i < 12; ++i) ((float4*)stats)[(i << 8) + tid] = z4;
    return;
  }
  const int flat = (bb - 321) * 256 + tid;   // 0..24575
  const int m = flat >= 12288;
  const int idx = flat - (m ? 12288 : 0);
  const float* src = m ? c3w : c2w;
  ushort* dst = m ? cwt3 : cwt2;
  const int o = idx / 192, rem = idx - o * 192;
  const int kk = rem >> 6, c = rem & 63;
  dst[idx] = f2bf(src[o * 192 + c * 3 + kk]);
}

// ---------------------------------------------------------------------------
// Stage 1: EdgeConv via count-matrix (R11). One block per graph.
// ---------------------------------------------------------------------------
__global__ __launch_bounds__(256) void k_edge(
    const float* __restrict__ x, const int* __restrict__ ei,
    const float* __restrict__ w1, const float* __restrict__ b1,
    const float* __restrict__ w2, const float* __restrict__ b2,
    ushort* __restrict__ out0, float* __restrict__ stats1)
{
  __shared__ float xs[64];
  __shared__ int   Mc[64][65];          // padded: stride 65 -> conflict-free
  __shared__ float aggC[64][8];
  __shared__ float w1s[8], b1s[4];
  __shared__ float w2s[256], b2s[64];
  __shared__ float rs[4][64], rss[4][64];
  const int tid = threadIdx.x;
  const int b = blockIdx.x;

  if (tid < 8) w1s[tid] = w1[tid];
  if (tid < 4) b1s[tid] = b1[tid];
  if (tid < 64) { xs[tid] = x[(b << 6) + tid]; b2s[tid] = b2[tid]; }
  w2s[tid] = w2[tid];
  for (int i = tid; i < 64 * 65; i += 256) ((int*)Mc)[i] = 0;
  __syncthreads();

  const int e0 = b * EPG;
  const int4 s4 = ((const int4*)(ei + e0))[tid];
  const int4 d4 = ((const int4*)(ei + NEDGE + e0))[tid];
  atomicAdd(&Mc[d4.x & 63][s4.x & 63], 1);
  atomicAdd(&Mc[d4.y & 63][s4.y & 63], 1);
  atomicAdd(&Mc[d4.z & 63][s4.z & 63], 1);
  atomicAdd(&Mc[d4.w & 63][s4.w & 63], 1);
  __syncthreads();

  // per (n,j): agg = sum_m Mc[n][m] * relu(w1[j]*x_n + w1[4+j]*(x_m-x_n) + b1[j])
  {
    const int n = tid & 63, j = tid >> 6;
    const float xn = xs[n];
    const float bj = w1s[4 + j];
    const float alpha = fmaf(xn, w1s[j] - bj, b1s[j]);
    float acc = 0.f;
    int dg = 0;
#pragma unroll 8
    for (int m = 0; m < 64; ++m) {
      const int c = Mc[n][m];
      const float h = fmaxf(fmaf(bj, xs[m], alpha), 0.f);
      acc += (float)c * h;
      dg += c;
    }
    aggC[n][j] = acc;
    if (j == 0) aggC[n][4] = (float)dg;
  }
  __syncthreads();

  const int c = tid & 63, qq = tid >> 6;
  const float wc0 = w2s[c], wc1 = w2s[64 + c], wc2 = w2s[128 + c], wc3 = w2s[192 + c];
  const float b2c = b2s[c];
  float s = 0.f, ss = 0.f;
  for (int n = qq; n < 64; n += 4) {
    const float4 a = *(const float4*)&aggC[n][0];
    const float dg = aggC[n][4];
    float v = a.x * wc0 + a.y * wc1 + a.z * wc2 + a.w * wc3 + dg * b2c;
    out0[(size_t)(((b << 6) + n) << 6) + c] = f2bf(v);
    s += v; ss += v * v;
  }
  rs[qq][c] = s; rss[qq][c] = ss;
  __syncthreads();
  if (tid < 64) {
    float* dst = stats1 + ((b & (REP - 1)) << 7);
    atomicAdd(&dst[tid], rs[0][tid] + rs[1][tid] + rs[2][tid] + rs[3][tid]);
    atomicAdd(&dst[64 + tid], rss[0][tid] + rss[1][tid] + rss[2][tid] + rss[3][tid]);
  }
}

// ---------------------------------------------------------------------------
// k_convm: BN + conv1d-as-MFMA; A-operand direct from global cwt (R12;
// valid because each A-row is register-reused across 4 MFMAs).
// ---------------------------------------------------------------------------
__global__ __launch_bounds__(256) void k_convm(
    const ushort* __restrict__ in,           // [1024][64 l][64 c] bf16
    const float* __restrict__ stats_in,      // [REP][128]
    const float* __restrict__ gamma, const float* __restrict__ beta,
    const ushort* __restrict__ cwt, const float* __restrict__ cb,
    ushort* __restrict__ out,                // [1024][64 l][64 o] bf16
    float* __restrict__ stats_out)           // [REP][128]
{
  __shared__ ushort Yt[66][72];
  __shared__ float aco[64], bco[64], cbs[64];
  __shared__ float ldsS[64], ldsSS[64];
  const int tid = threadIdx.x;
  const int b = blockIdx.x;

  if (tid < 64) {
    float sm = 0.f, sq = 0.f;
#pragma unroll 8
    for (int r = 0; r < REP; ++r) {
      sm += stats_in[(r << 7) + tid];
      sq += stats_in[(r << 7) + 64 + tid];
    }
    const float mean = sm * (1.0f / CNTF);
    const float var = sq * (1.0f / CNTF) - mean * mean;
    const float a = gamma[tid] * rsqrtf(var + EPSV);
    aco[tid] = a;
    bco[tid] = beta[tid] - mean * a;
    cbs[tid] = cb[tid];
    Yt[0][tid] = 0;
    Yt[65][tid] = 0;
  }
  __syncthreads();

  const size_t base = (size_t)b << 12;
  {
    const int lr = tid >> 2, p = (tid & 3) << 4;
    const ushort8 r0 = *(const ushort8*)&in[base + (lr << 6) + p];
    const ushort8 r1 = *(const ushort8*)&in[base + (lr << 6) + p + 8];
    ushort tmp[16];
#pragma unroll
    for (int j = 0; j < 8; ++j)
      tmp[j] = f2bf(fmaxf(fmaf(aco[p + j], bf2f(r0[j]), bco[p + j]), 0.f));
#pragma unroll
    for (int j = 0; j < 8; ++j)
      tmp[8 + j] = f2bf(fmaxf(fmaf(aco[p + 8 + j], bf2f(r1[j]), bco[p + 8 + j]), 0.f));
    *(ushort8*)&Yt[lr + 1][p] = *(ushort8*)&tmp[0];
    *(ushort8*)&Yt[lr + 1][p + 8] = *(ushort8*)&tmp[8];
  }
  __syncthreads();

  const int lane = tid & 63, w = tid >> 6;
  const int lm = lane & 15, q = lane >> 4;
  const ushort* arow = cwt + ((w << 4) + lm) * 192;   // this lane's A-row
  f32x4 acc[4];
#pragma unroll
  for (int nt = 0; nt < 4; ++nt) acc[nt] = (f32x4){0.f, 0.f, 0.f, 0.f};

#pragma unroll
  for (int kk = 0; kk < 3; ++kk) {
#pragma unroll
    for (int ks = 0; ks < 2; ++ks) {
      const short8 af = *(const short8*)&arow[(kk << 6) + (ks << 5) + (q << 3)];
#pragma unroll
      for (int nt = 0; nt < 4; ++nt) {
        const short8 bfr = *(const short8*)&Yt[(nt << 4) + lm + kk][(ks << 5) + (q << 3)];
        acc[nt] = __builtin_amdgcn_mfma_f32_16x16x32_bf16(af, bfr, acc[nt], 0, 0, 0);
      }
    }
  }

  const int obase = (w << 4) + (q << 2);
  const float4 cb4 = *(const float4*)&cbs[obase];
  float s[4] = {0.f, 0.f, 0.f, 0.f}, ss[4] = {0.f, 0.f, 0.f, 0.f};
#pragma unroll
  for (int nt = 0; nt < 4; ++nt) {
    const int l = (nt << 4) + lm;
    float4 v = make_float4(acc[nt][0] + cb4.x, acc[nt][1] + cb4.y,
                           acc[nt][2] + cb4.z, acc[nt][3] + cb4.w);
    *(ushort4*)&out[base + (l << 6) + obase] =
        make_ushort4(f2bf(v.x), f2bf(v.y), f2bf(v.z), f2bf(v.w));
    s[0] += v.x; ss[0] += v.x * v.x;
    s[1] += v.y; ss[1] += v.y * v.y;
    s[2] += v.z; ss[2] += v.z * v.z;
    s[3] += v.w; ss[3] += v.w * v.w;
  }
#pragma unroll
  for (int i = 0; i < 4; ++i) {
#pragma unroll
    for (int off = 1; off < 16; off <<= 1) {
      s[i] += __shfl_xor(s[i], off);
      ss[i] += __shfl_xor(ss[i], off);
    }
    if (lm == 0) { ldsS[obase + i] = s[i]; ldsSS[obase + i] = ss[i]; }
  }
  __syncthreads();
  if (tid < 64) {
    float* dst = stats_out + ((b & (REP - 1)) << 7);
    atomicAdd(&dst[tid], ldsS[tid]);
    atomicAdd(&dst[64 + tid], ldsSS[tid]);
  }
}

// ---------------------------------------------------------------------------
// k_mlp1: N-split version. Grid (16 Mtiles, 4 Ntiles of 64, 8 Ksplits)
// = 512 blocks (2/CU). Ys + Ws[64] staged in LDS; acc[4] per wave.
// ---------------------------------------------------------------------------
__global__ __launch_bounds__(256) void k_mlp1(
    const ushort* __restrict__ z3, const float* __restrict__ stats3,
    const float* __restrict__ g3, const float* __restrict__ be3,
    const ushort* __restrict__ wbf1t, float* __restrict__ h1part)
{
  __shared__ ushort Ys[64][72];
  __shared__ ushort Ws[64][72];
  __shared__ float a3s[64], b3s[64];
  const int tid = threadIdx.x;
  const int bx = blockIdx.x, by = blockIdx.y, bz = blockIdx.z;

  if (tid < 64) {
    float sm = 0.f, sq = 0.f;
#pragma unroll 8
    for (int r = 0; r < REP; ++r) {
      sm += stats3[(r << 7) + tid];
      sq += stats3[(r << 7) + 64 + tid];
    }
    const float mean = sm * (1.0f / CNTF);
    const float var = sq * (1.0f / CNTF) - mean * mean;
    const float a = g3[tid] * rsqrtf(var + EPSV);
    a3s[tid] = a;
    b3s[tid] = be3[tid] - mean * a;
  }
  __syncthreads();

  const int lane = tid & 63, w = tid >> 6;
  const int lm = lane & 15, q = lane >> 4;
  const int gy = tid >> 2, py = (tid & 3) << 4;   // Ys staging: graph, k-part
  const int g0 = bx << 6, n0 = by << 6;           // by in 0..3 -> 64-col tile

  f32x4 acc[4];
#pragma unroll
  for (int nt = 0; nt < 4; ++nt) acc[nt] = (f32x4){0.f, 0.f, 0.f, 0.f};

  const size_t ybase = ((size_t)(g0 + gy) << 12);

#pragma unroll 1
  for (int ck = 0; ck < 8; ++ck) {
    const int kc = (bz << 9) + (ck << 6);
    if (ck) __syncthreads();
    // --- stage Ys: BN3+ReLU on bf16 z3 (channel = within-chunk index)
    {
      const ushort* src = z3 + ybase + kc + py;
      const ushort8 r0 = *(const ushort8*)src;
      const ushort8 r1 = *(const ushort8*)(src + 8);
      ushort tmp[16];
#pragma unroll
      for (int j = 0; j < 8; ++j)
        tmp[j] = f2bf(fmaxf(fmaf(a3s[py + j], bf2f(r0[j]), b3s[py + j]), 0.f));
#pragma unroll
      for (int j = 0; j < 8; ++j)
        tmp[8 + j] = f2bf(fmaxf(fmaf(a3s[py + 8 + j], bf2f(r1[j]), b3s[py + 8 + j]), 0.f));
      *(ushort8*)&Ys[gy][py] = *(ushort8*)&tmp[0];
      *(ushort8*)&Ys[gy][py + 8] = *(ushort8*)&tmp[8];
    }
    // --- stage Ws: 64 rows x 8 ushort8 = 512 items over 256 threads
    {
      const ushort8* gw = (const ushort8*)(wbf1t + ((size_t)((bz << 3) + ck) << 14) + ((size_t)n0 << 6));
#pragma unroll
      for (int i = 0; i < 2; ++i) {
        const int e8 = (i << 8) + tid;
        const int n = e8 >> 3, kkp = (e8 & 7) << 3;
        *(ushort8*)&Ws[n][kkp] = gw[e8];
      }
    }
    __syncthreads();
#pragma unroll
    for (int ks = 0; ks < 2; ++ks) {
      const short8 af = *(const short8*)&Ys[(w << 4) + lm][(ks << 5) + (q << 3)];
#pragma unroll
      for (int nt = 0; nt < 4; ++nt) {
        const short8 bfr = *(const short8*)&Ws[(nt << 4) + lm][(ks << 5) + (q << 3)];
        acc[nt] = __builtin_amdgcn_mfma_f32_16x16x32_bf16(af, bfr, acc[nt], 0, 0, 0);
      }
    }
  }

  float* dst0 = h1part + ((size_t)bz << 18);
  const int gout = g0 + (w << 4) + (q << 2);
#pragma unroll
  for (int nt = 0; nt < 4; ++nt) {
    const int col = n0 + (nt << 4) + lm;
#pragma unroll
    for (int i = 0; i < 4; ++i)
      dst0[((size_t)(gout + i) << 8) + col] = acc[nt][i];
  }
}

// ---------------------------------------------------------------------------
// k_tail: h1 = relu(sum_bz h1part + bm1) -> h2 -> h3 -> logits -> logsoftmax.
// 64 blocks x 256 threads (proven champion form).
// ---------------------------------------------------------------------------
__global__ __launch_bounds__(256) void k_tail(
    const float* __restrict__ h1part, const float* __restrict__ bm1,
    const ushort* __restrict__ wbf2t, const float* __restrict__ bm2,
    const ushort* __restrict__ wbf3t, const float* __restrict__ bm3,
    const ushort* __restrict__ wptbf, const float* __restrict__ bp,
    float* __restrict__ out)
{
  __shared__ ushort Ws[256][72];
  __shared__ ushort h1s[16][264];
  __shared__ ushort h2s[16][264];
  ushort* wpt = &Ws[0][0];
  const int tid = threadIdx.x;
  const int g0 = blockIdx.x << 4;
  const int lane = tid & 63, w = tid >> 6;
  const int lm = lane & 15, q = lane >> 4;
  const int gr = q << 2;

  {
    const int r = tid >> 4, c0 = (tid & 15) << 4;
    const float* srcb = h1part + ((size_t)(g0 + r) << 8) + c0;
#pragma unroll
    for (int i = 0; i < 4; ++i) {
      float4 vs = *(const float4*)(bm1 + c0 + (i << 2));
#pragma unroll
      for (int bz = 0; bz < 8; ++bz) {
        const float4 p = *(const float4*)(srcb + ((size_t)bz << 18) + (i << 2));
        vs.x += p.x; vs.y += p.y; vs.z += p.z; vs.w += p.w;
      }
      *(ushort4*)&h1s[r][c0 + (i << 2)] = make_ushort4(
          f2bf(fmaxf(vs.x, 0.f)), f2bf(fmaxf(vs.y, 0.f)),
          f2bf(fmaxf(vs.z, 0.f)), f2bf(fmaxf(vs.w, 0.f)));
    }
  }

  // ---- GEMM2
  f32x4 acc[4];
#pragma unroll
  for (int nt = 0; nt < 4; ++nt) acc[nt] = (f32x4){0.f, 0.f, 0.f, 0.f};
#pragma unroll 1
  for (int ck = 0; ck < 4; ++ck) {
    __syncthreads();
    {
      const ushort8* gw = (const ushort8*)(wbf2t + (ck << 14));
#pragma unroll
      for (int i = 0; i < 8; ++i) {
        const int e8 = (i << 8) + tid;
        const int n = e8 >> 3, kk = (e8 & 7) << 3;
        *(ushort8*)&Ws[n][kk] = gw[e8];
      }
    }
    __syncthreads();
#pragma unroll
    for (int ks = 0; ks < 2; ++ks) {
      const short8 af = *(const short8*)&h1s[lm][(ck << 6) + (ks << 5) + (q << 3)];
#pragma unroll
      for (int nt = 0; nt < 4; ++nt) {
        const short8 bfr = *(const short8*)&Ws[(w << 6) + (nt << 4) + lm][(ks << 5) + (q << 3)];
        acc[nt] = __builtin_amdgcn_mfma_f32_16x16x32_bf16(af, bfr, acc[nt], 0, 0, 0);
      }
    }
  }
#pragma unroll
  for (int nt = 0; nt < 4; ++nt) {
    const int col = (w << 6) + (nt << 4) + lm;
    const float bv = bm2[col];
#pragma unroll
    for (int i = 0; i < 4; ++i)
      h2s[gr + i][col] = f2bf(fmaxf(acc[nt][i] + bv, 0.f));
  }

  // ---- GEMM3
  f32x4 acc2[4];
#pragma unroll
  for (int nt = 0; nt < 4; ++nt) acc2[nt] = (f32x4){0.f, 0.f, 0.f, 0.f};
#pragma unroll 1
  for (int ck = 0; ck < 4; ++ck) {
    __syncthreads();
    {
      const ushort8* gw = (const ushort8*)(wbf3t + (ck << 14));
#pragma unroll
      for (int i = 0; i < 8; ++i) {
        const int e8 = (i << 8) + tid;
        const int n = e8 >> 3, kk = (e8 & 7) << 3;
        *(ushort8*)&Ws[n][kk] = gw[e8];
      }
    }
    __syncthreads();
#pragma unroll
    for (int ks = 0; ks < 2; ++ks) {
      const short8 af = *(const short8*)&h2s[lm][(ck << 6) + (ks << 5) + (q << 3)];
#pragma unroll
      for (int nt = 0; nt < 4; ++nt) {
        const short8 bfr = *(const short8*)&Ws[(w << 6) + (nt << 4) + lm][(ks << 5) + (q << 3)];
        acc2[nt] = __builtin_amdgcn_mfma_f32_16x16x32_bf16(af, bfr, acc2[nt], 0, 0, 0);
      }
    }
  }

  __syncthreads();
  {
    const ushort8* gw = (const ushort8*)wptbf;
#pragma unroll
    for (int i = 0; i < 2; ++i) {
      const int e8 = (i << 8) + tid;
      const int flat = e8 << 3;
      const int a = flat >> 8, kk = flat & 255;
      *(ushort8*)&wpt[a * 264 + kk] = gw[e8];
    }
  }
#pragma unroll
  for (int nt = 0; nt < 4; ++nt) {
    const int col = (w << 6) + (nt << 4) + lm;
    const float bv = bm3[col];
#pragma unroll
    for (int i = 0; i < 4; ++i)
      h2s[gr + i][col] = f2bf(fmaxf(acc2[nt][i] + bv, 0.f));
  }
  __syncthreads();

  if (w == 0) {
    f32x4 lacc = (f32x4){0.f, 0.f, 0.f, 0.f};
#pragma unroll
    for (int ks = 0; ks < 8; ++ks) {
      const short8 af = *(const short8*)&h2s[lm][(ks << 5) + (q << 3)];
      const short8 bfr = *(const short8*)&wpt[lm * 264 + (ks << 5) + (q << 3)];
      lacc = __builtin_amdgcn_mfma_f32_16x16x32_bf16(af, bfr, lacc, 0, 0, 0);
    }
    const float bpv = bp[lm];
    float lg[4], mx[4], se[4];
#pragma unroll
    for (int i = 0; i < 4; ++i) {
      lg[i] = lacc[i] + bpv;
      float m = lg[i];
#pragma unroll
      for (int off = 1; off < 16; off <<= 1) m = fmaxf(m, __shfl_xor(m, off));
      mx[i] = m;
      float e = expf(lg[i] - m);
#pragma unroll
      for (int off = 1; off < 16; off <<= 1) e += __shfl_xor(e, off);
      se[i] = e;
    }
#pragma unroll
    for (int i = 0; i < 4; ++i)
      out[((g0 + gr + i) << 4) + lm] = (lg[i] - mx[i]) - logf(se[i]);
  }
}

// ---------------------------------------------------------------------------
extern "C" void kernel_launch(void* const* d_in, const int* in_sizes, int n_in,
                              void* d_out, int out_size, void* d_ws, size_t ws_size,
                              hipStream_t stream)
{
  const float* x   = (const float*)d_in[0];
  const int*   ei  = (const int*)d_in[1];
  const float* w1  = (const float*)d_in[2];
  const float* b1  = (const float*)d_in[3];
  const float* w2  = (const float*)d_in[4];
  const float* b2  = (const float*)d_in[5];
  const float* c2w = (const float*)d_in[6];
  const float* c2b = (const float*)d_in[7];
  const float* c3w = (const float*)d_in[8];
  const float* c3b = (const float*)d_in[9];
  const float* g1  = (const float*)d_in[10];
  const float* be1 = (const float*)d_in[11];
  const float* g2  = (const float*)d_in[12];
  const float* be2 = (const float*)d_in[13];
  const float* g3  = (const float*)d_in[14];
  const float* be3 = (const float*)d_in[15];
  const float* wm1 = (const float*)d_in[16];
  const float* bm1 = (const float*)d_in[17];
  const float* wm2 = (const float*)d_in[18];
  const float* bm2 = (const float*)d_in[19];
  const float* wm3 = (const float*)d_in[20];
  const float* bm3 = (const float*)d_in[21];
  const float* wp  = (const float*)d_in[22];
  const float* bp  = (const float*)d_in[23];

  char* ws = (char*)d_ws;
  ushort* ubuf0 = (ushort*)ws;                          // 8 MiB: out0 -> z3 (bf16)
  ushort* ubuf1 = (ushort*)(ws + ((size_t)8 << 20));    // 8 MiB: z2 (bf16)
  float*  h1part = (float*)(ws + ((size_t)16 << 20));   // 8 MiB fp32 partials
  ushort* wbf1t = (ushort*)(ws + ((size_t)24 << 20));   // 2 MiB bf16 wm1^T
  ushort* wbf2t = (ushort*)(ws + ((size_t)26 << 20));               // 128 KiB
  ushort* wbf3t = (ushort*)(ws + ((size_t)26 << 20) + (128 << 10)); // 128 KiB
  ushort* wptbf = (ushort*)(ws + ((size_t)26 << 20) + (256 << 10)); // 8 KiB
  float* stats = (float*)(ws + ((size_t)27 << 20));
  float* stats1 = stats;                  // [REP][128]
  float* stats2 = stats + REP * 128;
  float* stats3 = stats + 2 * REP * 128;
  ushort* cwt2 = (ushort*)d_out;          // d_out scratch, overwritten by k_tail
  ushort* cwt3 = (ushort*)d_out + 12288;

  k_prepw<<<dim3(418), dim3(256), 0, stream>>>(
      wm1, wm2, wm3, wp, c2w, c3w,
      wbf1t, wbf2t, wbf3t, wptbf, cwt2, cwt3, stats);
  k_edge<<<dim3(NB), dim3(256), 0, stream>>>(x, ei, w1, b1, w2, b2, ubuf0, stats1);
  k_convm<<<dim3(NB), dim3(256), 0, stream>>>(ubuf0, stats1, g1, be1, cwt2, c2b, ubuf1, stats2);
  k_convm<<<dim3(NB), dim3(256), 0, stream>>>(ubuf1, stats2, g2, be2, cwt3, c3b, ubuf0, stats3);
  k_mlp1<<<dim3(16, 4, 8), dim3(256), 0, stream>>>(ubuf0, stats3, g3, be3, wbf1t, h1part);
  k_tail<<<dim3(64), dim3(256), 0, stream>>>(h1part, bm1, wbf2t, bm2, wbf3t, bm3,
                                             wptbf, bp, (float*)d_out);
}